// Round 18
// baseline (114.450 us; speedup 1.0000x reference)
//
#include <hip/hip_runtime.h>
#include <hip/hip_bf16.h>

#define N_NODES 100000
#define IN_DIM 64
#define EMB 128
#define HID1 64
#define HID2 128
#define OUT_DIM 10

#define CHUNK 2048                       // edges per bin block (15.4KB LDS -> 10 blocks/CU)
#define EPT   (CHUNK / 256)              // 8 edges per thread in bin role
#define NBUCK ((N_NODES + 511) >> 9)     // 196 buckets of 512 nodes
#define CAPB 9216                        // fixed region per bucket (mean 8192 + 11.3 sigma)

#define NB_CONV ((N_NODES * 16) / 256)   // 6250 convert blocks
#define WCAT_N (128 * 128)
#define W1T_N  (64 * 128)
#define W2T_N  (128 * 64)
#define W3T_N  (16 * 128)
#define PREP_TOT (WCAT_N + W1T_N + W2T_N + W3T_N)
#define NB_PREP ((PREP_TOT + 255) / 256) // 136 prep blocks

using short8 = __attribute__((ext_vector_type(8))) short;
using bfx4   = __attribute__((ext_vector_type(4))) short;
using f32x4  = __attribute__((ext_vector_type(4))) float;

__device__ inline short f2bf(float f) {
  __hip_bfloat16 h = __float2bfloat16(f);
  return *reinterpret_cast<short*>(&h);
}

// ---------------- 1. fused front-end: bin_scatter | convert_x | prep_weights --
// pack = ((dst & 511) << 17) | src   (9 + 17 bits, src < 2^17)
struct BinShared {
  int hist[256], excl[256], cur[256], gb[256];
  int stage[CHUNK];
  unsigned char bof[CHUNK];
  int sc[256];
};

__global__ __launch_bounds__(256) void frontend_kernel(
    const float* __restrict__ x,
    const int* __restrict__ src, const int* __restrict__ dst,
    const float* __restrict__ W_l, const float* __restrict__ W_r,
    const float* __restrict__ W1, const float* __restrict__ W2,
    const float* __restrict__ W3,
    int* __restrict__ gcur, int* __restrict__ ebuf, short* __restrict__ xb,
    short* __restrict__ wcat_t, short* __restrict__ w1t,
    short* __restrict__ w2t, short* __restrict__ w3t,
    int E, int nbC)
{
  __shared__ __align__(16) char smem_raw[sizeof(BinShared)];
  const int b = blockIdx.x;
  const int tid = threadIdx.x;

  if (b < nbC) {
    // ---- role A: bin edges bucket-major into fixed-capacity regions ----
    BinShared& S = *reinterpret_cast<BinShared*>(smem_raw);
    const int base = b * CHUNK;
    const int cn = min(CHUNK, E - base);

    // one global pass over dst, cached in registers for hist and scatter
    int dreg[EPT];
#pragma unroll
    for (int it = 0; it < EPT; ++it) {
      int i = tid + it * 256;
      dreg[it] = (i < cn) ? dst[base + i] : -1;
    }

    S.hist[tid] = 0;
    __syncthreads();
#pragma unroll
    for (int it = 0; it < EPT; ++it)
      if (dreg[it] >= 0) atomicAdd(&S.hist[dreg[it] >> 9], 1);
    __syncthreads();

    int v = (tid < NBUCK) ? S.hist[tid] : 0;
    S.sc[tid] = v;
    __syncthreads();
    for (int off = 1; off < 256; off <<= 1) {
      int u = (tid >= off) ? S.sc[tid - off] : 0;
      __syncthreads();
      S.sc[tid] += u;
      __syncthreads();
    }
    {
      int ex = S.sc[tid] - v;
      S.excl[tid] = ex; S.cur[tid] = ex;
      S.gb[tid] = (tid < NBUCK && v) ? atomicAdd(&gcur[tid], v) : 0;
    }
    __syncthreads();

#pragma unroll
    for (int it = 0; it < EPT; ++it) {
      int i = tid + it * 256;
      if (i < cn) {
        int d = dreg[it], s = src[base + i];
        int bk = d >> 9;
        int pos = atomicAdd(&S.cur[bk], 1);
        S.stage[pos] = ((d & 511) << 17) | s;
        S.bof[pos] = (unsigned char)bk;
      }
    }
    __syncthreads();

    for (int i = tid; i < cn; i += 256) {
      int bk = S.bof[i];
      int idx = S.gb[bk] + (i - S.excl[bk]);
      if (idx < CAPB) ebuf[bk * CAPB + idx] = S.stage[i];  // clamp: never taken statistically
    }
  } else if (b < nbC + NB_CONV) {
    // ---- role B: convert x -> bf16 into dense xb[N][64] ----
    int t = (b - nbC) * 256 + tid;
    int node = t >> 4, g = t & 15;
    f32x4 v = *(const f32x4*)&x[(size_t)node * IN_DIM + g * 4];
    bfx4 s;
#pragma unroll
    for (int i = 0; i < 4; ++i) s[i] = f2bf(v[i]);
    *(bfx4*)&xb[((size_t)node << 6) + g * 4] = s;
  } else {
    // ---- role C: weight prep (bf16 transposed copies) ----
    int t = (b - nbC - NB_CONV) * 256 + tid;
    if (t < WCAT_N) {
      int c = t >> 7, k = t & 127;
      float v = (k < 64) ? W_r[k * EMB + c] : W_l[(k - 64) * EMB + c];
      wcat_t[c * 128 + k] = f2bf(v);
    } else if (t < WCAT_N + W1T_N) {
      int u = t - WCAT_N;
      int c = u >> 7, k = u & 127;
      w1t[c * 128 + k] = f2bf(W1[k * HID1 + c]);
    } else if (t < WCAT_N + W1T_N + W2T_N) {
      int u = t - WCAT_N - W1T_N;
      int c = u >> 6, k = u & 63;
      w2t[c * 64 + k] = f2bf(W2[k * HID2 + c]);
    } else if (t < PREP_TOT) {
      int u = t - WCAT_N - W1T_N - W2T_N;
      int c = u >> 7, k = u & 127;
      w3t[c * 128 + k] = (c < OUT_DIM) ? f2bf(W3[k * OUT_DIM + c]) : (short)0;
    }
  }
}

// ---------------- 2. per-bucket CSR finalize (in-place, LDS-staged) ----------
__global__ __launch_bounds__(256) void bucket_csr(
    const int* __restrict__ gcur, int* __restrict__ ebuf,
    int* __restrict__ offs, int* __restrict__ oend)
{
  __shared__ int cnt[512], cur[512], sc[512];
  __shared__ int ep[CAPB];
  __shared__ int es[CAPB];
  const int b = blockIdx.x, tid = threadIdx.x;
  const int node0 = b << 9;
  const int nn = min(512, N_NODES - node0);
  const int ebase = b * CAPB;
  const int ecnt = min(gcur[b], CAPB);

  for (int i = tid; i < 512; i += 256) cnt[i] = 0;
  __syncthreads();
  for (int i = tid; i < ecnt; i += 256) {
    int p = ebuf[ebase + i];
    ep[i] = p;
    atomicAdd(&cnt[p >> 17], 1);
  }
  __syncthreads();
  for (int i = tid; i < 512; i += 256) sc[i] = cnt[i];
  __syncthreads();
  for (int off = 1; off < 512; off <<= 1) {
    int i0 = tid, i1 = tid + 256;
    int v0 = (i0 >= off) ? sc[i0 - off] : 0;
    int v1 = (i1 >= off) ? sc[i1 - off] : 0;
    __syncthreads();
    sc[i0] += v0; sc[i1] += v1;
    __syncthreads();
  }
  for (int i = tid; i < 512; i += 256) {
    int ex = sc[i] - cnt[i];
    cur[i] = ex;
    if (i < nn) {
      offs[node0 + i] = ebase + ex;
      oend[node0 + i] = ebase + sc[i];
    }
  }
  __syncthreads();
  for (int i = tid; i < ecnt; i += 256) {
    int p = ep[i];
    int pos = atomicAdd(&cur[p >> 17], 1);
    es[pos] = p & 131071;
  }
  __syncthreads();
  for (int i = tid; i < ecnt; i += 256) ebuf[ebase + i] = es[i];
}

// ---------------- 3. gather-aggregate: mb[node] = bf16(mean) ----------
// One wave per node; scalar (readfirstlane) offs/oend/esrc reads. DWORD
// gathers: lane li in [0,32) covers dims 2li,2li+1; half-wave h=0 takes even
// edges, h=1 odd -> one wave-load covers TWO edges (8 loads per 16 edges,
// ~40% fewer issue slots than the ushort version). No shfl broadcast, so the
// even/odd tail divergence is harmless; the only shfl is the final uniform
// shfl_xor(32) combine. fp32 accumulate, 16 edges in flight.
__global__ __launch_bounds__(256) void aggregate_kernel(
    const int* __restrict__ offs, const int* __restrict__ oend,
    const int* __restrict__ esrc, const short* __restrict__ xb,
    short* __restrict__ mb)
{
  int wv = (int)((blockIdx.x * 256 + threadIdx.x) >> 6);
  const int lane = threadIdx.x & 63;
  const int node = __builtin_amdgcn_readfirstlane(wv);
  if (node >= N_NODES) return;
  const int h = lane >> 5, li = lane & 31;
  const int beg = offs[node];
  const int end = oend[node];
  const int deg = end - beg;
  const unsigned* cb = (const unsigned*)xb;   // dword view: node*32 + li
  float a0 = 0.f, a1 = 0.f;

  int k = beg;
  for (; k + 16 <= end; k += 16) {
    unsigned q0 = ((unsigned)esrc[k + 0  + h] << 5) + li;
    unsigned q1 = ((unsigned)esrc[k + 2  + h] << 5) + li;
    unsigned q2 = ((unsigned)esrc[k + 4  + h] << 5) + li;
    unsigned q3 = ((unsigned)esrc[k + 6  + h] << 5) + li;
    unsigned q4 = ((unsigned)esrc[k + 8  + h] << 5) + li;
    unsigned q5 = ((unsigned)esrc[k + 10 + h] << 5) + li;
    unsigned q6 = ((unsigned)esrc[k + 12 + h] << 5) + li;
    unsigned q7 = ((unsigned)esrc[k + 14 + h] << 5) + li;
    unsigned u0 = cb[q0], u1 = cb[q1], u2 = cb[q2], u3 = cb[q3];
    unsigned u4 = cb[q4], u5 = cb[q5], u6 = cb[q6], u7 = cb[q7];
    a0 += __uint_as_float(u0 << 16); a1 += __uint_as_float(u0 & 0xFFFF0000u);
    a0 += __uint_as_float(u1 << 16); a1 += __uint_as_float(u1 & 0xFFFF0000u);
    a0 += __uint_as_float(u2 << 16); a1 += __uint_as_float(u2 & 0xFFFF0000u);
    a0 += __uint_as_float(u3 << 16); a1 += __uint_as_float(u3 & 0xFFFF0000u);
    a0 += __uint_as_float(u4 << 16); a1 += __uint_as_float(u4 & 0xFFFF0000u);
    a0 += __uint_as_float(u5 << 16); a1 += __uint_as_float(u5 & 0xFFFF0000u);
    a0 += __uint_as_float(u6 << 16); a1 += __uint_as_float(u6 & 0xFFFF0000u);
    a0 += __uint_as_float(u7 << 16); a1 += __uint_as_float(u7 & 0xFFFF0000u);
  }
  if (k + 8 <= end) {
    unsigned q0 = ((unsigned)esrc[k + 0 + h] << 5) + li;
    unsigned q1 = ((unsigned)esrc[k + 2 + h] << 5) + li;
    unsigned q2 = ((unsigned)esrc[k + 4 + h] << 5) + li;
    unsigned q3 = ((unsigned)esrc[k + 6 + h] << 5) + li;
    unsigned u0 = cb[q0], u1 = cb[q1], u2 = cb[q2], u3 = cb[q3];
    a0 += __uint_as_float(u0 << 16); a1 += __uint_as_float(u0 & 0xFFFF0000u);
    a0 += __uint_as_float(u1 << 16); a1 += __uint_as_float(u1 & 0xFFFF0000u);
    a0 += __uint_as_float(u2 << 16); a1 += __uint_as_float(u2 & 0xFFFF0000u);
    a0 += __uint_as_float(u3 << 16); a1 += __uint_as_float(u3 & 0xFFFF0000u);
    k += 8;
  }
  if (k + 4 <= end) {
    unsigned q0 = ((unsigned)esrc[k + 0 + h] << 5) + li;
    unsigned q1 = ((unsigned)esrc[k + 2 + h] << 5) + li;
    unsigned u0 = cb[q0], u1 = cb[q1];
    a0 += __uint_as_float(u0 << 16); a1 += __uint_as_float(u0 & 0xFFFF0000u);
    a0 += __uint_as_float(u1 << 16); a1 += __uint_as_float(u1 & 0xFFFF0000u);
    k += 4;
  }
  if (k + 2 <= end) {
    unsigned q0 = ((unsigned)esrc[k + h] << 5) + li;
    unsigned u0 = cb[q0];
    a0 += __uint_as_float(u0 << 16); a1 += __uint_as_float(u0 & 0xFFFF0000u);
    k += 2;
  }
  if (k < end) {                 // one leftover edge: h=0 half only
    unsigned q0 = ((unsigned)esrc[k] << 5) + li;
    unsigned u0 = cb[q0];
    if (h == 0) {
      a0 += __uint_as_float(u0 << 16); a1 += __uint_as_float(u0 & 0xFFFF0000u);
    }
  }

  a0 += __shfl_xor(a0, 32, 64);
  a1 += __shfl_xor(a1, 32, 64);
  if (h == 0) {
    float d = fmaxf((float)deg, 1.0f);
    unsigned p = ((unsigned)(unsigned short)f2bf(a1 / d) << 16) |
                 (unsigned short)f2bf(a0 / d);
    ((unsigned*)mb)[((size_t)node << 5) + li] = p;
  }
}

// ---------------- 4. fused SAGEConv + MLP via bf16 MFMA (64-node tile) -------
// Weights are read DIRECTLY from global as B-fragments (L1/L2-resident,
// 68KB shared by all 1563 blocks). LDS 40KB -> 4 blocks/CU, 4 barriers.
#define PA 128
#define PH 64

__global__ __launch_bounds__(256) void fused_mfma_kernel(
    const short* __restrict__ xb, const short* __restrict__ mb,
    const short* __restrict__ wcat_t, const short* __restrict__ w1t,
    const short* __restrict__ w2t, const short* __restrict__ w3t,
    const float* __restrict__ b_l, const float* __restrict__ b1,
    const float* __restrict__ b2, const float* __restrict__ b3,
    float* __restrict__ out)
{
  __shared__ __align__(16) short sA0[64 * PA];   // x||mean input tile
  __shared__ __align__(16) short sH [64 * PA];   // h, later h2
  __shared__ __align__(16) short sH1[64 * PH];   // h1

  const int tid  = threadIdx.x;
  const int base = blockIdx.x * 64;
  const int lane = tid & 63;
  const int w    = tid >> 6;
  const int lrow = lane & 15;
  const int lgrp = lane >> 4;

  // ---- phase 0: stage A0 = [xb || mb] tile ----
  for (int T = tid; T < 1024; T += 256) {
    int n = T >> 4, g = T & 15;
    int node = base + n;
    short8 s = {0, 0, 0, 0, 0, 0, 0, 0};
    if (node < N_NODES) {
      const short* sp = (g < 8) ? &xb[((size_t)node << 6) + 8 * g]
                                : &mb[((size_t)node << 6) + 8 * (g - 8)];
      s = *(const short8*)sp;
    }
    *(short8*)&sA0[(n * PA + 8 * g) ^ ((n & 7) << 3)] = s;
  }
  __syncthreads();

  // ---- L1: H = A0 @ Wcat + b_l  (wave w: cols 32w..32w+31) ----
  {
    const int c0w = 32 * w;
    short8 bf[2][4];
#pragma unroll
    for (int ct = 0; ct < 2; ++ct)
#pragma unroll
      for (int kk = 0; kk < 4; ++kk) {
        int row = c0w + 16 * ct + lrow;
        bf[ct][kk] = *(const short8*)&wcat_t[row * 128 + kk * 32 + lgrp * 8];
      }
#pragma unroll
    for (int rt = 0; rt < 4; ++rt) {
      short8 af[4];
#pragma unroll
      for (int kk = 0; kk < 4; ++kk) {
        int row = rt * 16 + lrow;
        af[kk] = *(const short8*)&sA0[(row * PA + kk * 32 + lgrp * 8) ^ ((row & 7) << 3)];
      }
#pragma unroll
      for (int ct = 0; ct < 2; ++ct) {
        float bv = b_l[c0w + 16 * ct + lrow];
        f32x4 acc = {bv, bv, bv, bv};
#pragma unroll
        for (int kk = 0; kk < 4; ++kk)
          acc = __builtin_amdgcn_mfma_f32_16x16x32_bf16(af[kk], bf[ct][kk], acc, 0, 0, 0);
        int col = c0w + 16 * ct + lrow;
        int rb = rt * 16 + lgrp * 4;
#pragma unroll
        for (int r = 0; r < 4; ++r) {
          int row = rb + r;
          sH[(row * PA + col) ^ ((row & 7) << 3)] = f2bf(acc[r]);
        }
      }
    }
  }
  __syncthreads();

  // ---- L2: H1 = relu(H @ W1 + b1)  (wave w: cols 16w..16w+15) ----
  {
    const int c0 = 16 * w;
    short8 bf[4];
#pragma unroll
    for (int kk = 0; kk < 4; ++kk) {
      int row = c0 + lrow;
      bf[kk] = *(const short8*)&w1t[row * 128 + kk * 32 + lgrp * 8];
    }
#pragma unroll
    for (int rt = 0; rt < 4; ++rt) {
      short8 af[4];
#pragma unroll
      for (int kk = 0; kk < 4; ++kk) {
        int row = rt * 16 + lrow;
        af[kk] = *(const short8*)&sH[(row * PA + kk * 32 + lgrp * 8) ^ ((row & 7) << 3)];
      }
      float bv = b1[c0 + lrow];
      f32x4 acc = {bv, bv, bv, bv};
#pragma unroll
      for (int kk = 0; kk < 4; ++kk)
        acc = __builtin_amdgcn_mfma_f32_16x16x32_bf16(af[kk], bf[kk], acc, 0, 0, 0);
      int col = c0 + lrow;
      int rb = rt * 16 + lgrp * 4;
#pragma unroll
      for (int r = 0; r < 4; ++r) {
        int row = rb + r;
        sH1[(row * PH + col) ^ ((row & 7) << 3)] = f2bf(fmaxf(acc[r], 0.f));
      }
    }
  }
  __syncthreads();

  // ---- L3: H(h2) = relu(H1 @ W2 + b2)  (wave w: cols 32w..32w+31) ----
  {
    const int c0w = 32 * w;
    short8 bf[2][2];
#pragma unroll
    for (int ct = 0; ct < 2; ++ct)
#pragma unroll
      for (int kk = 0; kk < 2; ++kk) {
        int row = c0w + 16 * ct + lrow;
        bf[ct][kk] = *(const short8*)&w2t[row * 64 + kk * 32 + lgrp * 8];
      }
#pragma unroll
    for (int rt = 0; rt < 4; ++rt) {
      short8 af[2];
#pragma unroll
      for (int kk = 0; kk < 2; ++kk) {
        int row = rt * 16 + lrow;
        af[kk] = *(const short8*)&sH1[(row * PH + kk * 32 + lgrp * 8) ^ ((row & 7) << 3)];
      }
#pragma unroll
      for (int ct = 0; ct < 2; ++ct) {
        float bv = b2[c0w + 16 * ct + lrow];
        f32x4 acc = {bv, bv, bv, bv};
#pragma unroll
        for (int kk = 0; kk < 2; ++kk)
          acc = __builtin_amdgcn_mfma_f32_16x16x32_bf16(af[kk], bf[ct][kk], acc, 0, 0, 0);
        int col = c0w + 16 * ct + lrow;
        int rb = rt * 16 + lgrp * 4;
#pragma unroll
        for (int r = 0; r < 4; ++r) {
          int row = rb + r;
          sH[(row * PA + col) ^ ((row & 7) << 3)] = f2bf(fmaxf(acc[r], 0.f));
        }
      }
    }
  }
  __syncthreads();

  // ---- L4: out = h2 @ W3 + b3  (wave w: rows 16w..16w+15) ----
  {
    short8 af[4], bf[4];
#pragma unroll
    for (int kk = 0; kk < 4; ++kk) {
      int row = 16 * w + lrow;
      af[kk] = *(const short8*)&sH[(row * PA + kk * 32 + lgrp * 8) ^ ((row & 7) << 3)];
      bf[kk] = *(const short8*)&w3t[lrow * 128 + kk * 32 + lgrp * 8];
    }
    float bv = (lrow < OUT_DIM) ? b3[lrow] : 0.f;
    f32x4 acc = {bv, bv, bv, bv};
#pragma unroll
    for (int kk = 0; kk < 4; ++kk)
      acc = __builtin_amdgcn_mfma_f32_16x16x32_bf16(af[kk], bf[kk], acc, 0, 0, 0);
#pragma unroll
    for (int r = 0; r < 4; ++r) {
      int row = 16 * w + lgrp * 4 + r;
      int node = base + row;
      if (node < N_NODES && lrow < OUT_DIM)
        out[(long long)node * OUT_DIM + lrow] = acc[r];
    }
  }
}

extern "C" void kernel_launch(void* const* d_in, const int* in_sizes, int n_in,
                              void* d_out, int out_size, void* d_ws, size_t ws_size,
                              hipStream_t stream) {
  const float* x   = (const float*)d_in[0];
  const int*   ei  = (const int*)d_in[1];   // [2, E] int32
  const float* W_l = (const float*)d_in[2];
  const float* b_l = (const float*)d_in[3];
  const float* W_r = (const float*)d_in[4];
  const float* W1  = (const float*)d_in[5];
  const float* b1  = (const float*)d_in[6];
  const float* W2  = (const float*)d_in[7];
  const float* b2  = (const float*)d_in[8];
  const float* W3  = (const float*)d_in[9];
  const float* b3  = (const float*)d_in[10];
  float* out = (float*)d_out;

  const int E = in_sizes[1] / 2;
  const int* src = ei;
  const int* dst = ei + E;

  // ws layout: wcat_t | w1t | w2t | w3t (bf16) | xb [N][64] | mb [N][64] |
  //            offs [N] | oend [N] | ebuf [NBUCK*CAPB] | gcur [NBUCK]
  short* wcat_t = (short*)d_ws;
  short* w1t    = wcat_t + WCAT_N;
  short* w2t    = w1t + W1T_N;
  short* w3t    = w2t + W2T_N;
  short* xb     = w3t + W3T_N;
  short* mb     = xb + (size_t)N_NODES * 64;
  int*   offs   = (int*)(mb + (size_t)N_NODES * 64);
  int*   oend   = offs + N_NODES;
  int*   ebuf   = oend + N_NODES;
  int*   gcur   = ebuf + (size_t)NBUCK * CAPB;

  (void)hipMemsetAsync(gcur, 0, NBUCK * sizeof(int), stream);

  const int nbC = (E + CHUNK - 1) / CHUNK;   // 782 for E=1.6M
  frontend_kernel<<<nbC + NB_CONV + NB_PREP, 256, 0, stream>>>(
      x, src, dst, W_l, W_r, W1, W2, W3,
      gcur, ebuf, xb, wcat_t, w1t, w2t, w3t, E, nbC);

  bucket_csr<<<NBUCK, 256, 0, stream>>>(gcur, ebuf, offs, oend);

  int nbAgg = (N_NODES * 64 + 255) / 256;   // one wave per node
  aggregate_kernel<<<nbAgg, 256, 0, stream>>>(offs, oend, ebuf, xb, mb);

  int nbF = (N_NODES + 63) / 64;
  fused_mfma_kernel<<<nbF, 256, 0, stream>>>(xb, mb, wcat_t, w1t, w2t, w3t,
                                             b_l, b1, b2, b3, out);
}

// Round 19
// 110.258 us; speedup vs baseline: 1.0380x; 1.0380x over previous
//
#include <hip/hip_runtime.h>
#include <hip/hip_bf16.h>

#define N_NODES 100000
#define IN_DIM 64
#define EMB 128
#define HID1 64
#define HID2 128
#define OUT_DIM 10

#define CHUNK 4096                       // edges per bin block (24.6KB LDS -> 6 blocks/CU)
#define EPT   (CHUNK / 256)              // 16 edges per thread in bin role
#define NBUCK ((N_NODES + 511) >> 9)     // 196 buckets of 512 nodes
#define CAPB 9216                        // fixed region per bucket (mean 8192 + 11.3 sigma)

#define NB_CONV ((N_NODES * 16) / 256)   // 6250 convert blocks
#define WCAT_N (128 * 128)
#define W1T_N  (64 * 128)
#define W2T_N  (128 * 64)
#define W3T_N  (16 * 128)
#define PREP_TOT (WCAT_N + W1T_N + W2T_N + W3T_N)
#define NB_PREP ((PREP_TOT + 255) / 256) // 136 prep blocks

using short8 = __attribute__((ext_vector_type(8))) short;
using bfx4   = __attribute__((ext_vector_type(4))) short;
using f32x4  = __attribute__((ext_vector_type(4))) float;

__device__ inline short f2bf(float f) {
  __hip_bfloat16 h = __float2bfloat16(f);
  return *reinterpret_cast<short*>(&h);
}

// ---------------- 1. fused front-end: bin_scatter | convert_x | prep_weights --
struct BinShared {
  int hist[256], excl[256], cur[256], gb[256];
  int stage[CHUNK];
  unsigned char bof[CHUNK];
  int sc[256];
};

__global__ __launch_bounds__(256) void frontend_kernel(
    const float* __restrict__ x,
    const int* __restrict__ src, const int* __restrict__ dst,
    const float* __restrict__ W_l, const float* __restrict__ W_r,
    const float* __restrict__ W1, const float* __restrict__ W2,
    const float* __restrict__ W3,
    int* __restrict__ gcur, int* __restrict__ ebuf, short* __restrict__ comb,
    short* __restrict__ wcat_t, short* __restrict__ w1t,
    short* __restrict__ w2t, short* __restrict__ w3t,
    int E, int nbC)
{
  __shared__ __align__(16) char smem_raw[sizeof(BinShared)];
  const int b = blockIdx.x;
  const int tid = threadIdx.x;

  if (b < nbC) {
    // ---- role A: bin edges bucket-major into fixed-capacity regions ----
    // pack = ((dst & 511) << 17) | src   (9 + 17 bits, src < 2^17)
    BinShared& S = *reinterpret_cast<BinShared*>(smem_raw);
    const int base = b * CHUNK;
    const int cn = min(CHUNK, E - base);

    int dreg[EPT];
#pragma unroll
    for (int it = 0; it < EPT; ++it) {
      int i = tid + it * 256;
      dreg[it] = (i < cn) ? dst[base + i] : -1;
    }

    S.hist[tid] = 0;
    __syncthreads();
#pragma unroll
    for (int it = 0; it < EPT; ++it)
      if (dreg[it] >= 0) atomicAdd(&S.hist[dreg[it] >> 9], 1);
    __syncthreads();

    int v = (tid < NBUCK) ? S.hist[tid] : 0;
    S.sc[tid] = v;
    __syncthreads();
    for (int off = 1; off < 256; off <<= 1) {
      int u = (tid >= off) ? S.sc[tid - off] : 0;
      __syncthreads();
      S.sc[tid] += u;
      __syncthreads();
    }
    {
      int ex = S.sc[tid] - v;
      S.excl[tid] = ex; S.cur[tid] = ex;
      S.gb[tid] = (tid < NBUCK && v) ? atomicAdd(&gcur[tid], v) : 0;
    }
    __syncthreads();

#pragma unroll
    for (int it = 0; it < EPT; ++it) {
      int i = tid + it * 256;
      if (i < cn) {
        int d = dreg[it], s = src[base + i];
        int bk = d >> 9;
        int pos = atomicAdd(&S.cur[bk], 1);
        S.stage[pos] = ((d & 511) << 17) | s;
        S.bof[pos] = (unsigned char)bk;
      }
    }
    __syncthreads();

    for (int i = tid; i < cn; i += 256) {
      int bk = S.bof[i];
      int idx = S.gb[bk] + (i - S.excl[bk]);
      if (idx < CAPB) ebuf[bk * CAPB + idx] = S.stage[i];  // clamp: never taken statistically
    }
  } else if (b < nbC + NB_CONV) {
    // ---- role B: convert x -> bf16 into comb[:, 0:64] ----
    int t = (b - nbC) * 256 + tid;
    int node = t >> 4, g = t & 15;
    f32x4 v = *(const f32x4*)&x[(size_t)node * IN_DIM + g * 4];
    bfx4 s;
#pragma unroll
    for (int i = 0; i < 4; ++i) s[i] = f2bf(v[i]);
    *(bfx4*)&comb[((size_t)node << 7) + g * 4] = s;
  } else {
    // ---- role C: weight prep (bf16 transposed copies) ----
    int t = (b - nbC - NB_CONV) * 256 + tid;
    if (t < WCAT_N) {
      int c = t >> 7, k = t & 127;
      float v = (k < 64) ? W_r[k * EMB + c] : W_l[(k - 64) * EMB + c];
      wcat_t[c * 128 + k] = f2bf(v);
    } else if (t < WCAT_N + W1T_N) {
      int u = t - WCAT_N;
      int c = u >> 7, k = u & 127;
      w1t[c * 128 + k] = f2bf(W1[k * HID1 + c]);
    } else if (t < WCAT_N + W1T_N + W2T_N) {
      int u = t - WCAT_N - W1T_N;
      int c = u >> 6, k = u & 63;
      w2t[c * 64 + k] = f2bf(W2[k * HID2 + c]);
    } else if (t < PREP_TOT) {
      int u = t - WCAT_N - W1T_N - W2T_N;
      int c = u >> 7, k = u & 127;
      w3t[c * 128 + k] = (c < OUT_DIM) ? f2bf(W3[k * OUT_DIM + c]) : (short)0;
    }
  }
}

// ---------------- 2. per-bucket CSR finalize (in-place, LDS-staged) ----------
__global__ __launch_bounds__(256) void bucket_csr(
    const int* __restrict__ gcur, int* __restrict__ ebuf,
    int* __restrict__ offs, int* __restrict__ oend)
{
  __shared__ int cnt[512], cur[512], sc[512];
  __shared__ int ep[CAPB];
  __shared__ int es[CAPB];
  const int b = blockIdx.x, tid = threadIdx.x;
  const int node0 = b << 9;
  const int nn = min(512, N_NODES - node0);
  const int ebase = b * CAPB;
  const int ecnt = min(gcur[b], CAPB);

  for (int i = tid; i < 512; i += 256) cnt[i] = 0;
  __syncthreads();
  for (int i = tid; i < ecnt; i += 256) {
    int p = ebuf[ebase + i];
    ep[i] = p;
    atomicAdd(&cnt[p >> 17], 1);
  }
  __syncthreads();
  for (int i = tid; i < 512; i += 256) sc[i] = cnt[i];
  __syncthreads();
  for (int off = 1; off < 512; off <<= 1) {
    int i0 = tid, i1 = tid + 256;
    int v0 = (i0 >= off) ? sc[i0 - off] : 0;
    int v1 = (i1 >= off) ? sc[i1 - off] : 0;
    __syncthreads();
    sc[i0] += v0; sc[i1] += v1;
    __syncthreads();
  }
  for (int i = tid; i < 512; i += 256) {
    int ex = sc[i] - cnt[i];
    cur[i] = ex;
    if (i < nn) {
      offs[node0 + i] = ebase + ex;
      oend[node0 + i] = ebase + sc[i];
    }
  }
  __syncthreads();
  for (int i = tid; i < ecnt; i += 256) {
    int p = ep[i];
    int pos = atomicAdd(&cur[p >> 17], 1);
    es[pos] = p & 131071;
  }
  __syncthreads();
  for (int i = tid; i < ecnt; i += 256) ebuf[ebase + i] = es[i];
}

// ---------------- 3. gather-aggregate: comb[:,64:128] = bf16(mean) ----------
__global__ __launch_bounds__(256) void aggregate_kernel(
    const int* __restrict__ offs, const int* __restrict__ oend,
    const int* __restrict__ esrc, short* __restrict__ comb)
{
  int wv = (int)((blockIdx.x * 256 + threadIdx.x) >> 6);
  const int lane = threadIdx.x & 63;
  const int node = __builtin_amdgcn_readfirstlane(wv);
  if (node >= N_NODES) return;
  const int beg = offs[node];
  const int end = oend[node];
  const int deg = end - beg;
  const unsigned short* cb = (const unsigned short*)comb;
  float a = 0.f;

  int k = beg;
  for (; k + 16 <= end; k += 16) {
    unsigned o0  = ((unsigned)esrc[k]      << 7) + lane;
    unsigned o1  = ((unsigned)esrc[k + 1]  << 7) + lane;
    unsigned o2  = ((unsigned)esrc[k + 2]  << 7) + lane;
    unsigned o3  = ((unsigned)esrc[k + 3]  << 7) + lane;
    unsigned o4  = ((unsigned)esrc[k + 4]  << 7) + lane;
    unsigned o5  = ((unsigned)esrc[k + 5]  << 7) + lane;
    unsigned o6  = ((unsigned)esrc[k + 6]  << 7) + lane;
    unsigned o7  = ((unsigned)esrc[k + 7]  << 7) + lane;
    unsigned o8  = ((unsigned)esrc[k + 8]  << 7) + lane;
    unsigned o9  = ((unsigned)esrc[k + 9]  << 7) + lane;
    unsigned o10 = ((unsigned)esrc[k + 10] << 7) + lane;
    unsigned o11 = ((unsigned)esrc[k + 11] << 7) + lane;
    unsigned o12 = ((unsigned)esrc[k + 12] << 7) + lane;
    unsigned o13 = ((unsigned)esrc[k + 13] << 7) + lane;
    unsigned o14 = ((unsigned)esrc[k + 14] << 7) + lane;
    unsigned o15 = ((unsigned)esrc[k + 15] << 7) + lane;
    unsigned u0  = cb[o0],  u1  = cb[o1],  u2  = cb[o2],  u3  = cb[o3];
    unsigned u4  = cb[o4],  u5  = cb[o5],  u6  = cb[o6],  u7  = cb[o7];
    unsigned u8  = cb[o8],  u9  = cb[o9],  u10 = cb[o10], u11 = cb[o11];
    unsigned u12 = cb[o12], u13 = cb[o13], u14 = cb[o14], u15 = cb[o15];
    a += __uint_as_float(u0  << 16); a += __uint_as_float(u1  << 16);
    a += __uint_as_float(u2  << 16); a += __uint_as_float(u3  << 16);
    a += __uint_as_float(u4  << 16); a += __uint_as_float(u5  << 16);
    a += __uint_as_float(u6  << 16); a += __uint_as_float(u7  << 16);
    a += __uint_as_float(u8  << 16); a += __uint_as_float(u9  << 16);
    a += __uint_as_float(u10 << 16); a += __uint_as_float(u11 << 16);
    a += __uint_as_float(u12 << 16); a += __uint_as_float(u13 << 16);
    a += __uint_as_float(u14 << 16); a += __uint_as_float(u15 << 16);
  }
  if (k + 8 <= end) {
    unsigned o0 = ((unsigned)esrc[k]     << 7) + lane;
    unsigned o1 = ((unsigned)esrc[k + 1] << 7) + lane;
    unsigned o2 = ((unsigned)esrc[k + 2] << 7) + lane;
    unsigned o3 = ((unsigned)esrc[k + 3] << 7) + lane;
    unsigned o4 = ((unsigned)esrc[k + 4] << 7) + lane;
    unsigned o5 = ((unsigned)esrc[k + 5] << 7) + lane;
    unsigned o6 = ((unsigned)esrc[k + 6] << 7) + lane;
    unsigned o7 = ((unsigned)esrc[k + 7] << 7) + lane;
    unsigned u0 = cb[o0], u1 = cb[o1], u2 = cb[o2], u3 = cb[o3];
    unsigned u4 = cb[o4], u5 = cb[o5], u6 = cb[o6], u7 = cb[o7];
    a += __uint_as_float(u0 << 16); a += __uint_as_float(u1 << 16);
    a += __uint_as_float(u2 << 16); a += __uint_as_float(u3 << 16);
    a += __uint_as_float(u4 << 16); a += __uint_as_float(u5 << 16);
    a += __uint_as_float(u6 << 16); a += __uint_as_float(u7 << 16);
    k += 8;
  }
  if (k + 4 <= end) {
    unsigned o0 = ((unsigned)esrc[k]     << 7) + lane;
    unsigned o1 = ((unsigned)esrc[k + 1] << 7) + lane;
    unsigned o2 = ((unsigned)esrc[k + 2] << 7) + lane;
    unsigned o3 = ((unsigned)esrc[k + 3] << 7) + lane;
    unsigned u0 = cb[o0], u1 = cb[o1], u2 = cb[o2], u3 = cb[o3];
    a += __uint_as_float(u0 << 16); a += __uint_as_float(u1 << 16);
    a += __uint_as_float(u2 << 16); a += __uint_as_float(u3 << 16);
    k += 4;
  }
  for (; k < end; ++k) {
    unsigned u0 = cb[((unsigned)esrc[k] << 7) + lane];
    a += __uint_as_float(u0 << 16);
  }

  float m = a / fmaxf((float)deg, 1.0f);
  ((unsigned short*)comb)[((size_t)node << 7) + 64 + lane] =
      (unsigned short)f2bf(m);
}

// ---------------- 4. fused SAGEConv + MLP via bf16 MFMA ----------------
#define PA 128
#define PH 64

__global__ __launch_bounds__(256) void fused_mfma_kernel(
    const short* __restrict__ comb,
    const short* __restrict__ wcat_t, const short* __restrict__ w1t,
    const short* __restrict__ w2t, const short* __restrict__ w3t,
    const float* __restrict__ b_l, const float* __restrict__ b1,
    const float* __restrict__ b2, const float* __restrict__ b3,
    float* __restrict__ out)
{
  __shared__ __align__(16) short sA0[64 * PA];   // x||mean, later W3^T
  __shared__ __align__(16) short sH [64 * PA];   // h, later h2
  __shared__ __align__(16) short sH1[64 * PH];   // h1
  __shared__ __align__(16) short sW [128 * PA];  // current layer weights (B^T)

  const int tid  = threadIdx.x;
  const int base = blockIdx.x * 64;
  const int lane = tid & 63;
  const int w    = tid >> 6;
  const int lrow = lane & 15;
  const int lgrp = lane >> 4;

  // ---- phase 0: stage A0 = comb tile, sW = Wcat^T ----
  for (int T = tid; T < 1024; T += 256) {
    int n = T >> 4, g = T & 15;
    int node = base + n;
    short8 s = {0, 0, 0, 0, 0, 0, 0, 0};
    if (node < N_NODES) s = *(const short8*)&comb[(size_t)node * 128 + 8 * g];
    *(short8*)&sA0[(n * PA + 8 * g) ^ ((n & 7) << 3)] = s;
  }
  for (int T = tid; T < 2048; T += 256) {
    int c = T >> 4, kg = T & 15;
    *(short8*)&sW[(c * PA + 8 * kg) ^ ((c & 7) << 3)] =
        *(const short8*)&wcat_t[c * 128 + 8 * kg];
  }
  __syncthreads();

  // ---- L1: H = A0 @ Wcat + b_l ----
  {
    const int c0w = 32 * w;
    short8 bf[2][4];
#pragma unroll
    for (int ct = 0; ct < 2; ++ct)
#pragma unroll
      for (int kk = 0; kk < 4; ++kk) {
        int row = c0w + 16 * ct + lrow;
        bf[ct][kk] = *(const short8*)&sW[(row * PA + kk * 32 + lgrp * 8) ^ ((row & 7) << 3)];
      }
#pragma unroll
    for (int rt = 0; rt < 4; ++rt) {
      short8 af[4];
#pragma unroll
      for (int kk = 0; kk < 4; ++kk) {
        int row = rt * 16 + lrow;
        af[kk] = *(const short8*)&sA0[(row * PA + kk * 32 + lgrp * 8) ^ ((row & 7) << 3)];
      }
#pragma unroll
      for (int ct = 0; ct < 2; ++ct) {
        float bv = b_l[c0w + 16 * ct + lrow];
        f32x4 acc = {bv, bv, bv, bv};
#pragma unroll
        for (int kk = 0; kk < 4; ++kk)
          acc = __builtin_amdgcn_mfma_f32_16x16x32_bf16(af[kk], bf[ct][kk], acc, 0, 0, 0);
        int col = c0w + 16 * ct + lrow;
        int rb = rt * 16 + lgrp * 4;
#pragma unroll
        for (int r = 0; r < 4; ++r) {
          int row = rb + r;
          sH[(row * PA + col) ^ ((row & 7) << 3)] = f2bf(acc[r]);
        }
      }
    }
  }
  __syncthreads();

  // ---- phase 2: stage W1^T into sW, W3^T into sA0 rows 0..15 ----
  for (int T = tid; T < 1024; T += 256) {
    int c = T >> 4, kg = T & 15;
    *(short8*)&sW[(c * PA + 8 * kg) ^ ((c & 7) << 3)] =
        *(const short8*)&w1t[c * 128 + 8 * kg];
  }
  {
    int c = tid >> 4, kg = tid & 15;
    *(short8*)&sA0[(c * PA + 8 * kg) ^ ((c & 7) << 3)] =
        *(const short8*)&w3t[c * 128 + 8 * kg];
  }
  __syncthreads();

  // ---- L2: H1 = relu(H @ W1 + b1) ----
  {
    const int c0 = 16 * w;
    short8 bf[4];
#pragma unroll
    for (int kk = 0; kk < 4; ++kk) {
      int row = c0 + lrow;
      bf[kk] = *(const short8*)&sW[(row * PA + kk * 32 + lgrp * 8) ^ ((row & 7) << 3)];
    }
#pragma unroll
    for (int rt = 0; rt < 4; ++rt) {
      short8 af[4];
#pragma unroll
      for (int kk = 0; kk < 4; ++kk) {
        int row = rt * 16 + lrow;
        af[kk] = *(const short8*)&sH[(row * PA + kk * 32 + lgrp * 8) ^ ((row & 7) << 3)];
      }
      float bv = b1[c0 + lrow];
      f32x4 acc = {bv, bv, bv, bv};
#pragma unroll
      for (int kk = 0; kk < 4; ++kk)
        acc = __builtin_amdgcn_mfma_f32_16x16x32_bf16(af[kk], bf[kk], acc, 0, 0, 0);
      int col = c0 + lrow;
      int rb = rt * 16 + lgrp * 4;
#pragma unroll
      for (int r = 0; r < 4; ++r) {
        int row = rb + r;
        sH1[(row * PH + col) ^ ((row & 7) << 3)] = f2bf(fmaxf(acc[r], 0.f));
      }
    }
  }
  __syncthreads();

  // ---- phase 4: stage W2^T into sW ----
  for (int T = tid; T < 1024; T += 256) {
    int c = T >> 3, kg = T & 7;
    *(short8*)&sW[(c * PA + 8 * kg) ^ ((c & 7) << 3)] =
        *(const short8*)&w2t[c * 64 + 8 * kg];
  }
  __syncthreads();

  // ---- L3: H(h2) = relu(H1 @ W2 + b2) ----
  {
    const int c0w = 32 * w;
    short8 bf[2][2];
#pragma unroll
    for (int ct = 0; ct < 2; ++ct)
#pragma unroll
      for (int kk = 0; kk < 2; ++kk) {
        int row = c0w + 16 * ct + lrow;
        bf[ct][kk] = *(const short8*)&sW[(row * PA + kk * 32 + lgrp * 8) ^ ((row & 7) << 3)];
      }
#pragma unroll
    for (int rt = 0; rt < 4; ++rt) {
      short8 af[2];
#pragma unroll
      for (int kk = 0; kk < 2; ++kk) {
        int row = rt * 16 + lrow;
        af[kk] = *(const short8*)&sH1[(row * PH + kk * 32 + lgrp * 8) ^ ((row & 7) << 3)];
      }
#pragma unroll
      for (int ct = 0; ct < 2; ++ct) {
        float bv = b2[c0w + 16 * ct + lrow];
        f32x4 acc = {bv, bv, bv, bv};
#pragma unroll
        for (int kk = 0; kk < 2; ++kk)
          acc = __builtin_amdgcn_mfma_f32_16x16x32_bf16(af[kk], bf[ct][kk], acc, 0, 0, 0);
        int col = c0w + 16 * ct + lrow;
        int rb = rt * 16 + lgrp * 4;
#pragma unroll
        for (int r = 0; r < 4; ++r) {
          int row = rb + r;
          sH[(row * PA + col) ^ ((row & 7) << 3)] = f2bf(fmaxf(acc[r], 0.f));
        }
      }
    }
  }
  __syncthreads();

  // ---- L4: out = h2 @ W3 + b3 ----
  {
    short8 af[4], bf[4];
#pragma unroll
    for (int kk = 0; kk < 4; ++kk) {
      int row = 16 * w + lrow;
      af[kk] = *(const short8*)&sH[(row * PA + kk * 32 + lgrp * 8) ^ ((row & 7) << 3)];
      bf[kk] = *(const short8*)&sA0[(lrow * PA + kk * 32 + lgrp * 8) ^ ((lrow & 7) << 3)];
    }
    float bv = (lrow < OUT_DIM) ? b3[lrow] : 0.f;
    f32x4 acc = {bv, bv, bv, bv};
#pragma unroll
    for (int kk = 0; kk < 4; ++kk)
      acc = __builtin_amdgcn_mfma_f32_16x16x32_bf16(af[kk], bf[kk], acc, 0, 0, 0);
#pragma unroll
    for (int r = 0; r < 4; ++r) {
      int row = 16 * w + lgrp * 4 + r;
      int node = base + row;
      if (node < N_NODES && lrow < OUT_DIM)
        out[(long long)node * OUT_DIM + lrow] = acc[r];
    }
  }
}

extern "C" void kernel_launch(void* const* d_in, const int* in_sizes, int n_in,
                              void* d_out, int out_size, void* d_ws, size_t ws_size,
                              hipStream_t stream) {
  const float* x   = (const float*)d_in[0];
  const int*   ei  = (const int*)d_in[1];   // [2, E] int32
  const float* W_l = (const float*)d_in[2];
  const float* b_l = (const float*)d_in[3];
  const float* W_r = (const float*)d_in[4];
  const float* W1  = (const float*)d_in[5];
  const float* b1  = (const float*)d_in[6];
  const float* W2  = (const float*)d_in[7];
  const float* b2  = (const float*)d_in[8];
  const float* W3  = (const float*)d_in[9];
  const float* b3  = (const float*)d_in[10];
  float* out = (float*)d_out;

  const int E = in_sizes[1] / 2;
  const int* src = ei;
  const int* dst = ei + E;

  // ws layout: wcat_t | w1t | w2t | w3t (bf16) | comb [N][128] bf16 |
  //            offs [N] | oend [N] | ebuf [NBUCK*CAPB] | gcur [NBUCK]
  short* wcat_t = (short*)d_ws;
  short* w1t    = wcat_t + WCAT_N;
  short* w2t    = w1t + W1T_N;
  short* w3t    = w2t + W2T_N;
  short* comb   = w3t + W3T_N;
  int*   offs   = (int*)(comb + (size_t)N_NODES * 128);
  int*   oend   = offs + N_NODES;
  int*   ebuf   = oend + N_NODES;
  int*   gcur   = ebuf + (size_t)NBUCK * CAPB;

  (void)hipMemsetAsync(gcur, 0, NBUCK * sizeof(int), stream);

  const int nbC = (E + CHUNK - 1) / CHUNK;   // 391 for E=1.6M
  frontend_kernel<<<nbC + NB_CONV + NB_PREP, 256, 0, stream>>>(
      x, src, dst, W_l, W_r, W1, W2, W3,
      gcur, ebuf, comb, wcat_t, w1t, w2t, w3t, E, nbC);

  bucket_csr<<<NBUCK, 256, 0, stream>>>(gcur, ebuf, offs, oend);

  int nbAgg = (N_NODES * 64 + 255) / 256;   // one wave per node
  aggregate_kernel<<<nbAgg, 256, 0, stream>>>(offs, oend, ebuf, comb);

  int nbF = (N_NODES + 63) / 64;
  fused_mfma_kernel<<<nbF, 256, 0, stream>>>(comb, wcat_t, w1t, w2t, w3t,
                                             b_l, b1, b2, b3, out);
}